// Round 4
// baseline (278.581 us; speedup 1.0000x reference)
//
#include <hip/hip_runtime.h>
#include <hip/hip_bf16.h>
#include <cstdint>
#include <cstddef>

using bf16 = __hip_bfloat16;
typedef __attribute__((ext_vector_type(4))) float f32x4;
typedef __attribute__((ext_vector_type(8))) short bf16x8;

#define D_MODEL 1024
#define SEQ     2048
#define NB      4
#define NHEAD   16
#define DHEAD   64
#define NROWS   (NB * SEQ)   // 8192

__device__ __forceinline__ void load_lds16(const void* g, void* l) {
  __builtin_amdgcn_global_load_lds(
      (const __attribute__((address_space(1))) unsigned int*)g,
      (__attribute__((address_space(3))) unsigned int*)l, 16, 0, 0);
}

__device__ __forceinline__ unsigned short f2bf(float f) {
  bf16 h = __float2bfloat16(f);
  return *(unsigned short*)&h;
}

// Truncating pack: two f32 -> packed bf16 pair (low = a, high = b). ~1 v_perm.
__device__ __forceinline__ unsigned pk_trunc(float a, float b) {
  union { float f; unsigned u; } ca, cb;
  ca.f = a; cb.f = b;
  return (ca.u >> 16) | (cb.u & 0xffff0000u);
}

// ---------------- LayerNorm: fp32 in, bf16 out; one wave per row ----------------
__global__ __launch_bounds__(256) void ln_kernel(
    const float* __restrict__ x, const float* __restrict__ g,
    const float* __restrict__ bb, bf16* __restrict__ xn) {
  int row  = blockIdx.x * 4 + (threadIdx.x >> 6);
  int lane = threadIdx.x & 63;
  const float4* xr = (const float4*)(x + (size_t)row * D_MODEL);
  float v[16], s = 0.f;
#pragma unroll
  for (int i = 0; i < 4; i++) {
    float4 t = xr[lane + 64 * i];
    v[4 * i] = t.x; v[4 * i + 1] = t.y; v[4 * i + 2] = t.z; v[4 * i + 3] = t.w;
    s += t.x + t.y + t.z + t.w;
  }
#pragma unroll
  for (int off = 32; off; off >>= 1) s += __shfl_xor(s, off, 64);
  float mean = s * (1.f / D_MODEL);
  float vs = 0.f;
#pragma unroll
  for (int i = 0; i < 16; i++) { float d = v[i] - mean; vs += d * d; }
#pragma unroll
  for (int off = 32; off; off >>= 1) vs += __shfl_xor(vs, off, 64);
  float rstd = rsqrtf(vs * (1.f / D_MODEL) + 1e-5f);
  ushort4* op = (ushort4*)(xn + (size_t)row * D_MODEL);
#pragma unroll
  for (int i = 0; i < 4; i++) {
    float4 gv = ((const float4*)g)[lane + 64 * i];
    float4 bv = ((const float4*)bb)[lane + 64 * i];
    ushort4 o;
    o.x = f2bf((v[4 * i]     - mean) * rstd * gv.x + bv.x);
    o.y = f2bf((v[4 * i + 1] - mean) * rstd * gv.y + bv.y);
    o.z = f2bf((v[4 * i + 2] - mean) * rstd * gv.z + bv.z);
    o.w = f2bf((v[4 * i + 3] - mean) * rstd * gv.w + bv.w);
    op[lane + 64 * i] = o;
  }
}

// ------- Fused transpose of both weights: fp32 in[1024][C] -> bf16 out[C][1024] -------
__global__ __launch_bounds__(256) void transpose_kernel(
    const float* __restrict__ w_qkv, bf16* __restrict__ wqkvT,
    const float* __restrict__ w_fc, bf16* __restrict__ wfcT) {
  __shared__ float tile[32][33];
  const float* in; bf16* out; int C, c0;
  if (blockIdx.x < 96) { in = w_qkv; out = wqkvT; C = 3072; c0 = blockIdx.x * 32; }
  else                 { in = w_fc;  out = wfcT;  C = 1024; c0 = (blockIdx.x - 96) * 32; }
  int r0 = blockIdx.y * 32;
  int tx = threadIdx.x & 31, ty = threadIdx.x >> 5;
  for (int i = ty; i < 32; i += 8)
    tile[i][tx] = in[(size_t)(r0 + i) * C + c0 + tx];
  __syncthreads();
  for (int i = ty; i < 32; i += 8)
    out[(size_t)(c0 + i) * 1024 + r0 + tx] = __float2bfloat16(tile[tx][i]);
}

__device__ __forceinline__ void store_ct(bf16* p, float v)  { *p = __float2bfloat16(v); }
__device__ __forceinline__ void store_ct(float* p, float v) { *p = v; }

// ------- GEMM: C[M,N] = A[M,K](bf16) @ Bt[N,K](bf16)^T + bias(f32) (+resid f32) -------
// BK=64, XOR-swizzled LDS (16B chunk ^ (row&7)): balanced 8-reads/bank b128 frags.
// SPLIT=1: qkv gemm. cols [0,1024) = Q -> pre-scaled by 0.125*log2(e) (exp2-domain
// scores); cols [0,2048) -> qk[row*2048+col]; cols [2048,3072) -> vt transposed with
// a within-64 kv permutation matching the attn PV MFMA k-mapping:
//   kv = mt*16 + q4*4 + r  ->  p = (mt>>1)*32 + q4*8 + (mt&1)*4 + r
template <int SPLIT, int RESID, typename CT>
__global__ __launch_bounds__(256) void gemm_bt(
    const bf16* __restrict__ A, const bf16* __restrict__ Bt,
    const float* __restrict__ bias, const float* __restrict__ resid,
    CT* __restrict__ C, bf16* __restrict__ vt, int M, int N, int K) {
  __shared__ __attribute__((aligned(16))) bf16 Alds[128 * 64];  // 16 KB
  __shared__ __attribute__((aligned(16))) bf16 Blds[128 * 64];  // 16 KB
  int tid = threadIdx.x, wave = tid >> 6, lane = tid & 63;
  int ntiles = N >> 7;
  int bm = blockIdx.x / ntiles, bn = blockIdx.x % ntiles;
  int m0 = bm << 7, n0 = bn << 7;
  int wm = (wave >> 1) << 6, wn = (wave & 1) << 6;
  int srow = tid >> 3;                        // 0..31 (row within 32-row stage block)
  int sw8  = (((tid & 7) ^ (srow & 7)) << 3); // swizzled source chunk (elements)
  int frow = lane & 15, quad = lane >> 4;
  const bf16* Ap[4];
  const bf16* Bp[4];
#pragma unroll
  for (int s = 0; s < 4; s++) {
    Ap[s] = A  + (size_t)(m0 + s * 32 + srow) * K + sw8;
    Bp[s] = Bt + (size_t)(n0 + s * 32 + srow) * K + sw8;
  }
  f32x4 acc[4][4] = {};
  for (int k0 = 0; k0 < K; k0 += 64) {
    __syncthreads();
#pragma unroll
    for (int s = 0; s < 4; s++) {
      load_lds16(Ap[s], (char*)Alds + s * 4096 + tid * 16);
      load_lds16(Bp[s], (char*)Blds + s * 4096 + tid * 16);
      Ap[s] += 64; Bp[s] += 64;
    }
    __syncthreads();
    bf16x8 af[4][2], bv[4][2];
#pragma unroll
    for (int i = 0; i < 4; i++)
#pragma unroll
      for (int kk = 0; kk < 2; kk++) {
        int e = (((kk * 4 + quad) ^ (frow & 7)) << 3);
        af[i][kk] = *(const bf16x8*)&Alds[(wm + i * 16 + frow) * 64 + e];
        bv[i][kk] = *(const bf16x8*)&Blds[(wn + i * 16 + frow) * 64 + e];
      }
#pragma unroll
    for (int i = 0; i < 4; i++)
#pragma unroll
      for (int j = 0; j < 4; j++) {
        acc[i][j] = __builtin_amdgcn_mfma_f32_16x16x32_bf16(af[i][0], bv[j][0], acc[i][j], 0, 0, 0);
        acc[i][j] = __builtin_amdgcn_mfma_f32_16x16x32_bf16(af[i][1], bv[j][1], acc[i][j], 0, 0, 0);
      }
  }
#pragma unroll
  for (int i = 0; i < 4; i++) {
    int row0 = m0 + wm + i * 16 + (quad << 2);
#pragma unroll
    for (int j = 0; j < 4; j++) {
      int col = n0 + wn + j * 16 + frow;
      float bvs = bias[col];
      if (SPLIT && col >= 2048) {           // V third -> permuted transposed vt
        int hd = col - 2048;
        int b = row0 >> 11, seq0 = row0 & 2047;
        int within = seq0 & 63, mt = within >> 4, q4 = (within >> 2) & 3;
        int pos = (seq0 & ~63) + ((mt >> 1) << 5) + (q4 << 3) + ((mt & 1) << 2);
        ushort4 pk;
        pk.x = f2bf(acc[i][j][0] + bvs);
        pk.y = f2bf(acc[i][j][1] + bvs);
        pk.z = f2bf(acc[i][j][2] + bvs);
        pk.w = f2bf(acc[i][j][3] + bvs);
        *(ushort4*)&vt[((size_t)(b * 1024 + hd)) * SEQ + pos] = pk;
      } else {
        int stride = SPLIT ? 2048 : N;
        // Q pre-scale: 1/sqrt(64) * log2(e) -> scores come out in exp2 domain
        float scale = (SPLIT && col < 1024) ? 0.18033688f : 1.0f;
#pragma unroll
        for (int r = 0; r < 4; r++) {
          size_t idx = (size_t)(row0 + r) * stride + col;
          float val = (acc[i][j][r] + bvs) * scale;
          if (RESID) val += resid[idx];
          store_ct(&C[idx], val);
        }
      }
    }
  }
}

// ---- Flash attention helpers ----

// Stage one 64x64 bf16 K tile + one 64x64 V tile into LDS (global_load_lds x4).
__device__ __forceinline__ void stage_kv(
    const bf16* Kp0, const bf16* Kp1, const bf16* Vp0, const bf16* Vp1,
    bf16* KB, bf16* VB, int tid) {
  load_lds16(Kp0, (char*)KB + tid * 16);
  load_lds16(Kp1, (char*)KB + 4096 + tid * 16);
  load_lds16(Vp0, (char*)VB + tid * 16);
  load_lds16(Vp1, (char*)VB + 4096 + tid * 16);
}

// QK^T for one KV tile: S^T[kv][q], A = K[kv][d], B = Q(regs).
__device__ __forceinline__ void qk_phase(
    const bf16* KL, int frow, int e0, const bf16x8 (&qf)[2][2], f32x4 (&s)[4][2]) {
#pragma unroll
  for (int mt = 0; mt < 4; mt++) {
    bf16x8 af0 = *(const bf16x8*)&KL[(mt * 16 + frow) * 64 + e0];
    bf16x8 af1 = *(const bf16x8*)&KL[(mt * 16 + frow) * 64 + (e0 ^ 32)];
#pragma unroll
    for (int q2 = 0; q2 < 2; q2++) {
      s[mt][q2] = __builtin_amdgcn_mfma_f32_16x16x32_bf16(af0, qf[q2][0], s[mt][q2], 0, 0, 0);
      s[mt][q2] = __builtin_amdgcn_mfma_f32_16x16x32_bf16(af1, qf[q2][1], s[mt][q2], 0, 0, 0);
    }
  }
}

// T15 overlap core: exp(tile t) on VALU interleaved with PV(tile t-1) on the
// matrix pipe. pki = packed P of tile t-1 (consumed), pko = packed P of tile t
// (produced). The two are independent, so even a single in-order wave keeps
// both pipes fed; no reliance on cross-wave phase drift.
__device__ __forceinline__ void exp_pv_phase(
    const bf16* VL, int frow, int e0, const f32x4 (&s)[4][2],
    const uint2 (&pki)[2][4], uint2 (&pko)[2][4], f32x4 (&l4)[2], f32x4 (&o)[4][2]) {
#pragma unroll
  for (int c = 0; c < 4; c++) {
    // exp chunk (mt = c) -> pko
#pragma unroll
    for (int q2 = 0; q2 < 2; q2++) {
      f32x4 pv;
      pv[0] = __builtin_amdgcn_exp2f(s[c][q2][0]);
      pv[1] = __builtin_amdgcn_exp2f(s[c][q2][1]);
      pv[2] = __builtin_amdgcn_exp2f(s[c][q2][2]);
      pv[3] = __builtin_amdgcn_exp2f(s[c][q2][3]);
      l4[q2] += pv;
      pko[q2][c].x = pk_trunc(pv[0], pv[1]);
      pko[q2][c].y = pk_trunc(pv[2], pv[3]);
    }
    // PV chunk (dt = c), previous tile: uses pki + V(t-1)
    bf16x8 vf0 = *(const bf16x8*)&VL[(c * 16 + frow) * 64 + e0];
    bf16x8 vf1 = *(const bf16x8*)&VL[(c * 16 + frow) * 64 + (e0 ^ 32)];
#pragma unroll
    for (int q2 = 0; q2 < 2; q2++) {
      union { unsigned u[4]; bf16x8 v; } pf0, pf1;
      pf0.u[0] = pki[q2][0].x; pf0.u[1] = pki[q2][0].y;
      pf0.u[2] = pki[q2][1].x; pf0.u[3] = pki[q2][1].y;
      pf1.u[0] = pki[q2][2].x; pf1.u[1] = pki[q2][2].y;
      pf1.u[2] = pki[q2][3].x; pf1.u[3] = pki[q2][3].y;
      o[c][q2] = __builtin_amdgcn_mfma_f32_16x16x32_bf16(vf0, pf0.v, o[c][q2], 0, 0, 0);
      o[c][q2] = __builtin_amdgcn_mfma_f32_16x16x32_bf16(vf1, pf1.v, o[c][q2], 0, 0, 0);
    }
  }
}

// exp-only (pipeline prologue, tile 0: no previous PV)
__device__ __forceinline__ void exp_only(
    const f32x4 (&s)[4][2], uint2 (&pko)[2][4], f32x4 (&l4)[2]) {
#pragma unroll
  for (int c = 0; c < 4; c++)
#pragma unroll
    for (int q2 = 0; q2 < 2; q2++) {
      f32x4 pv;
      pv[0] = __builtin_amdgcn_exp2f(s[c][q2][0]);
      pv[1] = __builtin_amdgcn_exp2f(s[c][q2][1]);
      pv[2] = __builtin_amdgcn_exp2f(s[c][q2][2]);
      pv[3] = __builtin_amdgcn_exp2f(s[c][q2][3]);
      l4[q2] += pv;
      pko[q2][c].x = pk_trunc(pv[0], pv[1]);
      pko[q2][c].y = pk_trunc(pv[2], pv[3]);
    }
}

// PV-only (pipeline epilogue, last tile)
__device__ __forceinline__ void pv_only(
    const bf16* VL, int frow, int e0, const uint2 (&pki)[2][4], f32x4 (&o)[4][2]) {
#pragma unroll
  for (int c = 0; c < 4; c++) {
    bf16x8 vf0 = *(const bf16x8*)&VL[(c * 16 + frow) * 64 + e0];
    bf16x8 vf1 = *(const bf16x8*)&VL[(c * 16 + frow) * 64 + (e0 ^ 32)];
#pragma unroll
    for (int q2 = 0; q2 < 2; q2++) {
      union { unsigned u[4]; bf16x8 v; } pf0, pf1;
      pf0.u[0] = pki[q2][0].x; pf0.u[1] = pki[q2][0].y;
      pf0.u[2] = pki[q2][1].x; pf0.u[3] = pki[q2][1].y;
      pf1.u[0] = pki[q2][2].x; pf1.u[1] = pki[q2][2].y;
      pf1.u[2] = pki[q2][3].x; pf1.u[3] = pki[q2][3].y;
      o[c][q2] = __builtin_amdgcn_mfma_f32_16x16x32_bf16(vf0, pf0.v, o[c][q2], 0, 0, 0);
      o[c][q2] = __builtin_amdgcn_mfma_f32_16x16x32_bf16(vf1, pf1.v, o[c][q2], 0, 0, 0);
    }
  }
}

// One software-pipelined tile: stage(t+1), QK(t), exp(t) // PV(t-1), barrier.
__device__ __forceinline__ void tile_body(
    const bf16* Ks0, const bf16* Ks1, const bf16* Vs0, const bf16* Vs1,
    bf16* Ksd, bf16* Vsd, const bf16* Krd, const bf16* Vrd,
    int tid, int frow, int e0, const bf16x8 (&qf)[2][2],
    const uint2 (&pki)[2][4], uint2 (&pko)[2][4], f32x4 (&l4)[2], f32x4 (&o)[4][2]) {
  stage_kv(Ks0, Ks1, Vs0, Vs1, Ksd, Vsd, tid);
  f32x4 s[4][2] = {};
  qk_phase(Krd, frow, e0, qf, s);
  exp_pv_phase(Vrd, frow, e0, s, pki, pko, l4, o);
  __syncthreads();
}

// ---- Flash attention (S^T form, exp2-domain, no-max softmax, register-P) ----
// v3: T15 double-pipeline. Per tile t: QK(t) -> { exp(t) on VALU || PV(t-1) on
// matrix pipe } -- breaks the measured matrix/VALU phase lockstep (r3 counters:
// MfmaUtil 38 + VALUBusy 48 summing to ~duration = fully serialized pipes).
// V triple-buffered (PV lags one tile), K double-buffered: LDS = 40 KB, still
// 4 blocks/CU (4 x 40 = 160 KB). Loop unrolled x6 (lcm of K%2, V%3) so all
// buffer indices and pk-array roles are compile-time. One barrier per tile.
__global__ __launch_bounds__(256, 4) void attn_kernel(
    const bf16* __restrict__ qk, const bf16* __restrict__ vt,
    bf16* __restrict__ aout) {
  int bh = blockIdx.x;   // 0..63 == b*16+h
  int qt = blockIdx.y;   // 0..15
  int bb = bh >> 4, h = bh & 15;
  const bf16* Qg = qk + (size_t)bb * SEQ * 2048 + h * DHEAD;
  const bf16* Kg = Qg + D_MODEL;
  const bf16* Vg = vt + (size_t)bh * DHEAD * SEQ;

  // 40 KB pool: [K0 8K][K1 8K][V0 8K][V1 8K][V2 8K]; Q staged into K0+K1.
  __shared__ __attribute__((aligned(16))) bf16 pool[20480];
  bf16* Kb0 = pool;
  bf16* Kb1 = pool + 4096;
  bf16* V0  = pool + 8192;
  bf16* V1  = pool + 12288;
  bf16* V2  = pool + 16384;

  int tid = threadIdx.x, wave = tid >> 6, lane = tid & 63;
  int prow = tid >> 3, pch = tid & 7;
  int lch8 = ((pch ^ (prow & 7)) << 3);   // swizzled global elem offset (staging)
  int frow = lane & 15, quad = lane >> 4;
  int e0 = ((quad ^ (frow & 7)) << 3);    // swizzled phys elem offset (frag reads)
  int q0 = qt * 128;

  const bf16* Kp0 = Kg + (size_t)prow * 2048 + lch8;
  const bf16* Kp1 = Kg + (size_t)(32 + prow) * 2048 + lch8;
  const bf16* Vp0 = Vg + (size_t)prow * SEQ + lch8;
  const bf16* Vp1 = Vg + (size_t)(32 + prow) * SEQ + lch8;
  const size_t KT = (size_t)1 << 17;   // 64 rows * 2048 elems

  // ---- Prologue: stage Q into K0+K1 (16 KB); hoist Q fragments ----
#pragma unroll
  for (int s2 = 0; s2 < 4; s2++)
    load_lds16(Qg + (size_t)(q0 + s2 * 32 + prow) * 2048 + lch8,
               (char*)pool + s2 * 4096 + tid * 16);
  __syncthreads();
  bf16x8 qf[2][2];  // B-operand: n=q, k=d
#pragma unroll
  for (int q2 = 0; q2 < 2; q2++)
#pragma unroll
    for (int kk = 0; kk < 2; kk++)
      qf[q2][kk] =
          *(const bf16x8*)&pool[(wave * 32 + q2 * 16 + frow) * 64 + (e0 ^ (kk * 32))];
  __syncthreads();  // all waves done reading Q -> K buffers reusable

  // Stage tiles 0 and 1 (both K buffers + V0,V1 free)
  stage_kv(Kp0, Kp1, Vp0, Vp1, Kb0, V0, tid);
  stage_kv(Kp0 + KT, Kp1 + KT, Vp0 + 64, Vp1 + 64, Kb1, V1, tid);
  __syncthreads();  // vmcnt(0): tiles 0,1 resident

  f32x4 l4[2] = {};
  f32x4 o[4][2] = {};     // O^T accumulators: [d-tile][q-tile]
  uint2 pkA[2][4], pkB[2][4];

  // Peel t=0: QK(0) + exp(0) -> pkB (no PV yet)
  {
    f32x4 s[4][2] = {};
    qk_phase(Kb0, frow, e0, qf, s);
    exp_only(s, pkB, l4);
  }
  __syncthreads();

  // Advance base to tile 1
  Kp0 += KT; Kp1 += KT; Vp0 += 64; Vp1 += 64;

  // ---- Main loop: t = 1..30, unrolled x6. Body t: stage(t+1), QK(t),
  // exp(t)||PV(t-1), barrier.  K[t&1] read / K[(t+1)&1] staged;
  // V[(t-1)%3] read (PV) / V[(t+1)%3] staged. pk arrays alternate by t parity.
#pragma unroll 1
  for (int kt = 1; kt <= 25; kt += 6) {
    tile_body(Kp0 + 1*KT, Kp1 + 1*KT, Vp0 + 1*64, Vp1 + 1*64, Kb0, V2, Kb1, V0,
              tid, frow, e0, qf, pkB, pkA, l4, o);                       // t%6==1
    tile_body(Kp0 + 2*KT, Kp1 + 2*KT, Vp0 + 2*64, Vp1 + 2*64, Kb1, V0, Kb0, V1,
              tid, frow, e0, qf, pkA, pkB, l4, o);                       // t%6==2
    tile_body(Kp0 + 3*KT, Kp1 + 3*KT, Vp0 + 3*64, Vp1 + 3*64, Kb0, V1, Kb1, V2,
              tid, frow, e0, qf, pkB, pkA, l4, o);                       // t%6==3
    tile_body(Kp0 + 4*KT, Kp1 + 4*KT, Vp0 + 4*64, Vp1 + 4*64, Kb1, V2, Kb0, V0,
              tid, frow, e0, qf, pkA, pkB, l4, o);                       // t%6==4
    tile_body(Kp0 + 5*KT, Kp1 + 5*KT, Vp0 + 5*64, Vp1 + 5*64, Kb0, V0, Kb1, V1,
              tid, frow, e0, qf, pkB, pkA, l4, o);                       // t%6==5
    tile_body(Kp0 + 6*KT, Kp1 + 6*KT, Vp0 + 6*64, Vp1 + 6*64, Kb1, V1, Kb0, V2,
              tid, frow, e0, qf, pkA, pkB, l4, o);                       // t%6==0
    Kp0 += 6 * KT; Kp1 += 6 * KT; Vp0 += 6 * 64; Vp1 += 6 * 64;
  }

  // Peel t=31 (no staging): QK(31) from K1 (staged at t=30), exp(31)->pkA,
  // PV(30) from V0 (tile 30 staged at t=29).
  {
    f32x4 s[4][2] = {};
    qk_phase(Kb1, frow, e0, qf, s);
    exp_pv_phase(V0, frow, e0, s, pkB, pkA, l4, o);
  }
  // Final PV(31): V1 holds tile 31 (staged at t=30), pkA holds P(31).
  pv_only(V1, frow, e0, pkA, o);

  // l = sum over kv: horizontal (4 regs) + cross-quad (lanes ^16, ^32)
  float linv[2];
#pragma unroll
  for (int q2 = 0; q2 < 2; q2++) {
    float v = (l4[q2][0] + l4[q2][1]) + (l4[q2][2] + l4[q2][3]);
    v += __shfl_xor(v, 16, 64);
    v += __shfl_xor(v, 32, 64);
    linv[q2] = 1.f / v;
  }

  // Normalize, transpose O^T -> O through dead LDS (per-wave region), store.
  __syncthreads();  // all waves done reading final K/V tiles
  bf16* Tw = pool + wave * 2560;   // 32 rows x stride 80 = 5120 B per wave
#pragma unroll
  for (int q2 = 0; q2 < 2; q2++)
#pragma unroll
    for (int dt = 0; dt < 4; dt++) {
      ushort4 pk;
      pk.x = f2bf(o[dt][q2][0] * linv[q2]);
      pk.y = f2bf(o[dt][q2][1] * linv[q2]);
      pk.z = f2bf(o[dt][q2][2] * linv[q2]);
      pk.w = f2bf(o[dt][q2][3] * linv[q2]);
      *(ushort4*)&Tw[(q2 * 16 + frow) * 80 + dt * 16 + quad * 4] = pk;
    }
  int rq = lane >> 1, d0 = (lane & 1) * 32;
  size_t grow = (size_t)(bb * SEQ + q0 + wave * 32 + rq);
#pragma unroll
  for (int i = 0; i < 4; i++) {
    bf16x8 v8 = *(const bf16x8*)&Tw[rq * 80 + d0 + i * 8];
    *(bf16x8*)&aout[grow * D_MODEL + h * DHEAD + d0 + i * 8] = v8;
  }
}

extern "C" void kernel_launch(void* const* d_in, const int* in_sizes, int n_in,
                              void* d_out, int out_size, void* d_ws, size_t ws_size,
                              hipStream_t stream) {
  const float* x     = (const float*)d_in[0];
  const float* w_qkv = (const float*)d_in[1];
  const float* b_qkv = (const float*)d_in[2];
  const float* w_fc  = (const float*)d_in[3];
  const float* b_fc  = (const float*)d_in[4];
  const float* ln_g  = (const float*)d_in[5];
  const float* ln_b  = (const float*)d_in[6];
  float* out = (float*)d_out;

  char* ws = (char*)d_ws;
  bf16* xn    = (bf16*)(ws);                 // 16 MB (aliased by aout after gemm1)
  bf16* wqkvT = (bf16*)(ws + (16u << 20));   //  6 MB
  bf16* wfcT  = (bf16*)(ws + (22u << 20));   //  2 MB
  bf16* qk    = (bf16*)(ws + (24u << 20));   // 32 MB
  bf16* vt    = (bf16*)(ws + (56u << 20));   // 16 MB -> 72 MB total
  bf16* aout  = (bf16*)(ws);                 // reuses xn region

  ln_kernel<<<NROWS / 4, 256, 0, stream>>>(x, ln_g, ln_b, xn);
  transpose_kernel<<<dim3(128, 32), 256, 0, stream>>>(w_qkv, wqkvT, w_fc, wfcT);
  gemm_bt<1, 0, bf16><<<(NROWS / 128) * (3 * D_MODEL / 128), 256, 0, stream>>>(
      xn, wqkvT, b_qkv, nullptr, qk, vt, NROWS, 3 * D_MODEL, D_MODEL);
  attn_kernel<<<dim3(NB * NHEAD, SEQ / 128), 256, 0, stream>>>(qk, vt, aout);
  gemm_bt<0, 1, float><<<(NROWS / 128) * (D_MODEL / 128), 256, 0, stream>>>(
      aout, wfcT, b_fc, x, out, nullptr, NROWS, D_MODEL, D_MODEL);
}

// Round 5
// 270.681 us; speedup vs baseline: 1.0292x; 1.0292x over previous
//
#include <hip/hip_runtime.h>
#include <hip/hip_bf16.h>
#include <cstdint>
#include <cstddef>

using bf16 = __hip_bfloat16;
typedef __attribute__((ext_vector_type(4))) float f32x4;
typedef __attribute__((ext_vector_type(8))) short bf16x8;

#define D_MODEL 1024
#define SEQ     2048
#define NB      4
#define NHEAD   16
#define DHEAD   64
#define NROWS   (NB * SEQ)   // 8192

__device__ __forceinline__ void load_lds16(const void* g, void* l) {
  __builtin_amdgcn_global_load_lds(
      (const __attribute__((address_space(1))) unsigned int*)g,
      (__attribute__((address_space(3))) unsigned int*)l, 16, 0, 0);
}

__device__ __forceinline__ unsigned short f2bf(float f) {
  bf16 h = __float2bfloat16(f);
  return *(unsigned short*)&h;
}

// Truncating pack: two f32 -> packed bf16 pair (low = a, high = b). ~1 v_perm.
__device__ __forceinline__ unsigned pk_trunc(float a, float b) {
  union { float f; unsigned u; } ca, cb;
  ca.f = a; cb.f = b;
  return (ca.u >> 16) | (cb.u & 0xffff0000u);
}

// ---------------- LayerNorm: fp32 in, bf16 out; one wave per row ----------------
__global__ __launch_bounds__(256) void ln_kernel(
    const float* __restrict__ x, const float* __restrict__ g,
    const float* __restrict__ bb, bf16* __restrict__ xn) {
  int row  = blockIdx.x * 4 + (threadIdx.x >> 6);
  int lane = threadIdx.x & 63;
  const float4* xr = (const float4*)(x + (size_t)row * D_MODEL);
  float v[16], s = 0.f;
#pragma unroll
  for (int i = 0; i < 4; i++) {
    float4 t = xr[lane + 64 * i];
    v[4 * i] = t.x; v[4 * i + 1] = t.y; v[4 * i + 2] = t.z; v[4 * i + 3] = t.w;
    s += t.x + t.y + t.z + t.w;
  }
#pragma unroll
  for (int off = 32; off; off >>= 1) s += __shfl_xor(s, off, 64);
  float mean = s * (1.f / D_MODEL);
  float vs = 0.f;
#pragma unroll
  for (int i = 0; i < 16; i++) { float d = v[i] - mean; vs += d * d; }
#pragma unroll
  for (int off = 32; off; off >>= 1) vs += __shfl_xor(vs, off, 64);
  float rstd = rsqrtf(vs * (1.f / D_MODEL) + 1e-5f);
  ushort4* op = (ushort4*)(xn + (size_t)row * D_MODEL);
#pragma unroll
  for (int i = 0; i < 4; i++) {
    float4 gv = ((const float4*)g)[lane + 64 * i];
    float4 bv = ((const float4*)bb)[lane + 64 * i];
    ushort4 o;
    o.x = f2bf((v[4 * i]     - mean) * rstd * gv.x + bv.x);
    o.y = f2bf((v[4 * i + 1] - mean) * rstd * gv.y + bv.y);
    o.z = f2bf((v[4 * i + 2] - mean) * rstd * gv.z + bv.z);
    o.w = f2bf((v[4 * i + 3] - mean) * rstd * gv.w + bv.w);
    op[lane + 64 * i] = o;
  }
}

// ------- Fused transpose of both weights: fp32 in[1024][C] -> bf16 out[C][1024] -------
__global__ __launch_bounds__(256) void transpose_kernel(
    const float* __restrict__ w_qkv, bf16* __restrict__ wqkvT,
    const float* __restrict__ w_fc, bf16* __restrict__ wfcT) {
  __shared__ float tile[32][33];
  const float* in; bf16* out; int C, c0;
  if (blockIdx.x < 96) { in = w_qkv; out = wqkvT; C = 3072; c0 = blockIdx.x * 32; }
  else                 { in = w_fc;  out = wfcT;  C = 1024; c0 = (blockIdx.x - 96) * 32; }
  int r0 = blockIdx.y * 32;
  int tx = threadIdx.x & 31, ty = threadIdx.x >> 5;
  for (int i = ty; i < 32; i += 8)
    tile[i][tx] = in[(size_t)(r0 + i) * C + c0 + tx];
  __syncthreads();
  for (int i = ty; i < 32; i += 8)
    out[(size_t)(c0 + i) * 1024 + r0 + tx] = __float2bfloat16(tile[tx][i]);
}

__device__ __forceinline__ void store_ct(bf16* p, float v)  { *p = __float2bfloat16(v); }
__device__ __forceinline__ void store_ct(float* p, float v) { *p = v; }

// ------- GEMM (2-barrier 128x128 structure; used for the out-proj gemm only) -------
template <int SPLIT, int RESID, typename CT>
__global__ __launch_bounds__(256) void gemm_bt(
    const bf16* __restrict__ A, const bf16* __restrict__ Bt,
    const float* __restrict__ bias, const float* __restrict__ resid,
    CT* __restrict__ C, bf16* __restrict__ vt, int M, int N, int K) {
  __shared__ __attribute__((aligned(16))) bf16 Alds[128 * 64];  // 16 KB
  __shared__ __attribute__((aligned(16))) bf16 Blds[128 * 64];  // 16 KB
  int tid = threadIdx.x, wave = tid >> 6, lane = tid & 63;
  int ntiles = N >> 7;
  int bm = blockIdx.x / ntiles, bn = blockIdx.x % ntiles;
  int m0 = bm << 7, n0 = bn << 7;
  int wm = (wave >> 1) << 6, wn = (wave & 1) << 6;
  int srow = tid >> 3;                        // 0..31 (row within 32-row stage block)
  int sw8  = (((tid & 7) ^ (srow & 7)) << 3); // swizzled source chunk (elements)
  int frow = lane & 15, quad = lane >> 4;
  const bf16* Ap[4];
  const bf16* Bp[4];
#pragma unroll
  for (int s = 0; s < 4; s++) {
    Ap[s] = A  + (size_t)(m0 + s * 32 + srow) * K + sw8;
    Bp[s] = Bt + (size_t)(n0 + s * 32 + srow) * K + sw8;
  }
  f32x4 acc[4][4] = {};
  for (int k0 = 0; k0 < K; k0 += 64) {
    __syncthreads();
#pragma unroll
    for (int s = 0; s < 4; s++) {
      load_lds16(Ap[s], (char*)Alds + s * 4096 + tid * 16);
      load_lds16(Bp[s], (char*)Blds + s * 4096 + tid * 16);
      Ap[s] += 64; Bp[s] += 64;
    }
    __syncthreads();
    bf16x8 af[4][2], bv[4][2];
#pragma unroll
    for (int i = 0; i < 4; i++)
#pragma unroll
      for (int kk = 0; kk < 2; kk++) {
        int e = (((kk * 4 + quad) ^ (frow & 7)) << 3);
        af[i][kk] = *(const bf16x8*)&Alds[(wm + i * 16 + frow) * 64 + e];
        bv[i][kk] = *(const bf16x8*)&Blds[(wn + i * 16 + frow) * 64 + e];
      }
#pragma unroll
    for (int i = 0; i < 4; i++)
#pragma unroll
      for (int j = 0; j < 4; j++) {
        acc[i][j] = __builtin_amdgcn_mfma_f32_16x16x32_bf16(af[i][0], bv[j][0], acc[i][j], 0, 0, 0);
        acc[i][j] = __builtin_amdgcn_mfma_f32_16x16x32_bf16(af[i][1], bv[j][1], acc[i][j], 0, 0, 0);
      }
  }
#pragma unroll
  for (int i = 0; i < 4; i++) {
    int row0 = m0 + wm + i * 16 + (quad << 2);
#pragma unroll
    for (int j = 0; j < 4; j++) {
      int col = n0 + wn + j * 16 + frow;
      float bvs = bias[col];
      if (SPLIT && col >= 2048) {
        int hd = col - 2048;
        int b = row0 >> 11, seq0 = row0 & 2047;
        int within = seq0 & 63, mt = within >> 4, q4 = (within >> 2) & 3;
        int pos = (seq0 & ~63) + ((mt >> 1) << 5) + (q4 << 3) + ((mt & 1) << 2);
        ushort4 pk;
        pk.x = f2bf(acc[i][j][0] + bvs);
        pk.y = f2bf(acc[i][j][1] + bvs);
        pk.z = f2bf(acc[i][j][2] + bvs);
        pk.w = f2bf(acc[i][j][3] + bvs);
        *(ushort4*)&vt[((size_t)(b * 1024 + hd)) * SEQ + pos] = pk;
      } else {
        int stride = SPLIT ? 2048 : N;
        float scale = (SPLIT && col < 1024) ? 0.18033688f : 1.0f;
#pragma unroll
        for (int r = 0; r < 4; r++) {
          size_t idx = (size_t)(row0 + r) * stride + col;
          float val = (acc[i][j][r] + bvs) * scale;
          if (RESID) val += resid[idx];
          store_ct(&C[idx], val);
        }
      }
    }
  }
}

// ======== 8-phase 256x192 QKV GEMM (T1+T2+T3+T4+T5), 512 threads ========
// C[8192,3072] = xn[8192,1024] @ wqkvT[3072,1024]^T + b_qkv, SPLIT epilogue.
// BM=256 BN=192 BK=64; waves 2Mx4N; per-wave 128x48 = acc[8][3].
// LDS: (256+192)*64*2B double-buffered = 112 KB -> 1 block/CU, 2 waves/SIMD.
// Grid 512 = exactly 2 full rounds of 256 CUs; XCD-swizzled (512%8==0).
// Per K-tile: 4 phases x {ds_read subtile; BAR; lgkm(0); prio1 12xMFMA prio0; BAR}.
// All 7 stage loads (A:4,B:3) for tile t+1 issue at tile t phase 0; single
// vmcnt(0) at tile t phase 3 (those loads are ~3 phases old -> wait is free;
// loads for t+2 are not yet issued, so nothing young is drained).

template <bool STG>
__device__ __forceinline__ void ktile_qkv(
    const bf16* Aw, const bf16* Bw,            // cur buffers (wave-offset)
    bf16* Ad, bf16* Bd,                        // stage destinations (other buf)
    const bf16* const* Ab, const bf16* const* Bb, size_t koff,
    int tid, int frow, int e_lo, int e_hi, f32x4 (&acc)[8][3]) {
  __builtin_amdgcn_sched_barrier(0);
  // ---- phase 0: all B frags + A frags m={0,1}; stage next tile
  bf16x8 bv[3][2];
#pragma unroll
  for (int j = 0; j < 3; j++) {
    bv[j][0] = *(const bf16x8*)&Bw[(j * 16 + frow) * 64 + e_lo];
    bv[j][1] = *(const bf16x8*)&Bw[(j * 16 + frow) * 64 + e_hi];
  }
  bf16x8 a00 = *(const bf16x8*)&Aw[(frow) * 64 + e_lo];
  bf16x8 a01 = *(const bf16x8*)&Aw[(frow) * 64 + e_hi];
  bf16x8 a10 = *(const bf16x8*)&Aw[(16 + frow) * 64 + e_lo];
  bf16x8 a11 = *(const bf16x8*)&Aw[(16 + frow) * 64 + e_hi];
  if (STG) {
#pragma unroll
    for (int u = 0; u < 4; u++)
      load_lds16(Ab[u] + koff, (char*)Ad + u * 8192 + tid * 16);
#pragma unroll
    for (int u = 0; u < 3; u++)
      load_lds16(Bb[u] + koff, (char*)Bd + u * 8192 + tid * 16);
  }
  __builtin_amdgcn_s_barrier();
  asm volatile("s_waitcnt lgkmcnt(0)" ::: "memory");
  __builtin_amdgcn_sched_barrier(0);     // rule #18: keep MFMA below the wait
  __builtin_amdgcn_s_setprio(1);
#pragma unroll
  for (int j = 0; j < 3; j++) {
    acc[0][j] = __builtin_amdgcn_mfma_f32_16x16x32_bf16(a00, bv[j][0], acc[0][j], 0, 0, 0);
    acc[0][j] = __builtin_amdgcn_mfma_f32_16x16x32_bf16(a01, bv[j][1], acc[0][j], 0, 0, 0);
    acc[1][j] = __builtin_amdgcn_mfma_f32_16x16x32_bf16(a10, bv[j][0], acc[1][j], 0, 0, 0);
    acc[1][j] = __builtin_amdgcn_mfma_f32_16x16x32_bf16(a11, bv[j][1], acc[1][j], 0, 0, 0);
  }
  __builtin_amdgcn_s_setprio(0);
  __builtin_amdgcn_s_barrier();
  // ---- phases 1..3: A frags m={2p,2p+1}
#pragma unroll
  for (int p = 1; p < 4; p++) {
    bf16x8 c00 = *(const bf16x8*)&Aw[((2 * p) * 16 + frow) * 64 + e_lo];
    bf16x8 c01 = *(const bf16x8*)&Aw[((2 * p) * 16 + frow) * 64 + e_hi];
    bf16x8 c10 = *(const bf16x8*)&Aw[((2 * p + 1) * 16 + frow) * 64 + e_lo];
    bf16x8 c11 = *(const bf16x8*)&Aw[((2 * p + 1) * 16 + frow) * 64 + e_hi];
    __builtin_amdgcn_s_barrier();
    asm volatile("s_waitcnt lgkmcnt(0)" ::: "memory");
    __builtin_amdgcn_sched_barrier(0);
    __builtin_amdgcn_s_setprio(1);
#pragma unroll
    for (int j = 0; j < 3; j++) {
      acc[2 * p][j]     = __builtin_amdgcn_mfma_f32_16x16x32_bf16(c00, bv[j][0], acc[2 * p][j], 0, 0, 0);
      acc[2 * p][j]     = __builtin_amdgcn_mfma_f32_16x16x32_bf16(c01, bv[j][1], acc[2 * p][j], 0, 0, 0);
      acc[2 * p + 1][j] = __builtin_amdgcn_mfma_f32_16x16x32_bf16(c10, bv[j][0], acc[2 * p + 1][j], 0, 0, 0);
      acc[2 * p + 1][j] = __builtin_amdgcn_mfma_f32_16x16x32_bf16(c11, bv[j][1], acc[2 * p + 1][j], 0, 0, 0);
    }
    __builtin_amdgcn_s_setprio(0);
    if (p == 3) {
      asm volatile("s_waitcnt vmcnt(0)" ::: "memory");   // drain tile t+1's 7 loads (old)
      __builtin_amdgcn_sched_barrier(0);
    }
    __builtin_amdgcn_s_barrier();
  }
}

__global__ __launch_bounds__(512, 2) void gemm256_qkv(
    const bf16* __restrict__ A, const bf16* __restrict__ Bt,
    const float* __restrict__ bias, bf16* __restrict__ C, bf16* __restrict__ vt) {
  __shared__ __attribute__((aligned(16))) bf16 AL0[256 * 64];
  __shared__ __attribute__((aligned(16))) bf16 AL1[256 * 64];
  __shared__ __attribute__((aligned(16))) bf16 BL0[192 * 64];
  __shared__ __attribute__((aligned(16))) bf16 BL1[192 * 64];

  // T1: XCD-aware bijective swizzle (512 % 8 == 0): each XCD gets 64
  // consecutive logical tiles -> 4 shared A-panels per XCD + B reuse in L2.
  int bid = blockIdx.x;
  int logical = (bid & 7) * 64 + (bid >> 3);
  int bm = logical >> 4;          // 0..31
  int bn = logical & 15;          // 0..15
  int m0 = bm * 256, n0 = bn * 192;

  int tid = threadIdx.x, wave = tid >> 6, lane = tid & 63;
  int wm = (wave >> 2) * 128;     // 2 M-waves
  int wn = (wave & 3) * 48;       // 4 N-waves
  int srow = tid >> 3;            // 0..63 (row within 64-row stage unit)
  int sw8 = (((tid & 7) ^ (srow & 7)) << 3);
  int frow = lane & 15, quad = lane >> 4;
  int e_lo = ((quad ^ (frow & 7)) << 3);
  int e_hi = (((4 + quad) ^ (frow & 7)) << 3);

  const bf16* Ab[4];
  const bf16* Bb[3];
#pragma unroll
  for (int u = 0; u < 4; u++) Ab[u] = A + (size_t)(m0 + u * 64 + srow) * 1024 + sw8;
#pragma unroll
  for (int u = 0; u < 3; u++) Bb[u] = Bt + (size_t)(n0 + u * 64 + srow) * 1024 + sw8;

  // Prologue: stage K-tile 0 -> buf0, full drain, barrier.
#pragma unroll
  for (int u = 0; u < 4; u++) load_lds16(Ab[u], (char*)AL0 + u * 8192 + tid * 16);
#pragma unroll
  for (int u = 0; u < 3; u++) load_lds16(Bb[u], (char*)BL0 + u * 8192 + tid * 16);
  asm volatile("s_waitcnt vmcnt(0)" ::: "memory");
  __builtin_amdgcn_sched_barrier(0);
  __builtin_amdgcn_s_barrier();

  f32x4 acc[8][3] = {};
  const bf16* A0w = AL0 + wm * 64;
  const bf16* B0w = BL0 + wn * 64;
  const bf16* A1w = AL1 + wm * 64;
  const bf16* B1w = BL1 + wn * 64;

  // 16 K-tiles. Loop covers tiles 0..13 (7 x 2), peel 14 (stages L15) and 15.
  size_t ko = 64;
#pragma unroll 1
  for (int t2 = 0; t2 < 14; t2 += 2) {
    ktile_qkv<true>(A0w, B0w, AL1, BL1, Ab, Bb, ko,      tid, frow, e_lo, e_hi, acc);
    ktile_qkv<true>(A1w, B1w, AL0, BL0, Ab, Bb, ko + 64, tid, frow, e_lo, e_hi, acc);
    ko += 128;
  }
  ktile_qkv<true >(A0w, B0w, AL1, BL1, Ab, Bb, ko, tid, frow, e_lo, e_hi, acc);  // t=14
  ktile_qkv<false>(A1w, B1w, AL0, BL0, Ab, Bb, 0,  tid, frow, e_lo, e_hi, acc);  // t=15

  // ---- SPLIT epilogue (identical math to gemm_bt<1,0,bf16>) ----
#pragma unroll
  for (int i = 0; i < 8; i++) {
    int row0 = m0 + wm + i * 16 + (quad << 2);
#pragma unroll
    for (int j = 0; j < 3; j++) {
      int col = n0 + wn + j * 16 + frow;
      float bvs = bias[col];
      if (col >= 2048) {            // V third -> permuted transposed vt
        int hd = col - 2048;
        int b = row0 >> 11, seq0 = row0 & 2047;
        int within = seq0 & 63, mt = within >> 4, q4 = (within >> 2) & 3;
        int pos = (seq0 & ~63) + ((mt >> 1) << 5) + (q4 << 3) + ((mt & 1) << 2);
        ushort4 pk;
        pk.x = f2bf(acc[i][j][0] + bvs);
        pk.y = f2bf(acc[i][j][1] + bvs);
        pk.z = f2bf(acc[i][j][2] + bvs);
        pk.w = f2bf(acc[i][j][3] + bvs);
        *(ushort4*)&vt[((size_t)(b * 1024 + hd)) * SEQ + pos] = pk;
      } else {
        float scale = (col < 1024) ? 0.18033688f : 1.0f;
#pragma unroll
        for (int r = 0; r < 4; r++) {
          size_t idx = (size_t)(row0 + r) * 2048 + col;
          C[idx] = __float2bfloat16((acc[i][j][r] + bvs) * scale);
        }
      }
    }
  }
}

// ---- Flash attention helpers (round-3 version: simple dbuf, one barrier/tile) ----

__device__ __forceinline__ void stage_kv(
    const bf16* Kp0, const bf16* Kp1, const bf16* Vp0, const bf16* Vp1,
    bf16* KB, bf16* VB, int tid) {
  load_lds16(Kp0, (char*)KB + tid * 16);
  load_lds16(Kp1, (char*)KB + 4096 + tid * 16);
  load_lds16(Vp0, (char*)VB + tid * 16);
  load_lds16(Vp1, (char*)VB + 4096 + tid * 16);
}

// One KV tile: S^T = K @ Q^T; p = 2^s packed to bf16 in-register; O^T += V^T @ P^T.
__device__ __forceinline__ void kv_tile(
    const bf16* KL, const bf16* VL, int frow, int e0,
    const bf16x8 (&qf)[2][2], f32x4 (&l4)[2], f32x4 (&o)[4][2]) {
  f32x4 s[4][2] = {};
#pragma unroll
  for (int mt = 0; mt < 4; mt++) {
    bf16x8 af0 = *(const bf16x8*)&KL[(mt * 16 + frow) * 64 + e0];
    bf16x8 af1 = *(const bf16x8*)&KL[(mt * 16 + frow) * 64 + (e0 ^ 32)];
#pragma unroll
    for (int qt2 = 0; qt2 < 2; qt2++) {
      s[mt][qt2] = __builtin_amdgcn_mfma_f32_16x16x32_bf16(af0, qf[qt2][0], s[mt][qt2], 0, 0, 0);
      s[mt][qt2] = __builtin_amdgcn_mfma_f32_16x16x32_bf16(af1, qf[qt2][1], s[mt][qt2], 0, 0, 0);
    }
  }
  uint2 pk[2][4];
#pragma unroll
  for (int qt2 = 0; qt2 < 2; qt2++)
#pragma unroll
    for (int mt = 0; mt < 4; mt++) {
      f32x4 pv;
      pv[0] = __builtin_amdgcn_exp2f(s[mt][qt2][0]);
      pv[1] = __builtin_amdgcn_exp2f(s[mt][qt2][1]);
      pv[2] = __builtin_amdgcn_exp2f(s[mt][qt2][2]);
      pv[3] = __builtin_amdgcn_exp2f(s[mt][qt2][3]);
      l4[qt2] += pv;
      pk[qt2][mt].x = pk_trunc(pv[0], pv[1]);
      pk[qt2][mt].y = pk_trunc(pv[2], pv[3]);
    }
#pragma unroll
  for (int dt = 0; dt < 4; dt++) {
    bf16x8 vf0 = *(const bf16x8*)&VL[(dt * 16 + frow) * 64 + e0];
    bf16x8 vf1 = *(const bf16x8*)&VL[(dt * 16 + frow) * 64 + (e0 ^ 32)];
#pragma unroll
    for (int qt2 = 0; qt2 < 2; qt2++) {
      union { unsigned u[4]; bf16x8 v; } pf0, pf1;
      pf0.u[0] = pk[qt2][0].x; pf0.u[1] = pk[qt2][0].y;
      pf0.u[2] = pk[qt2][1].x; pf0.u[3] = pk[qt2][1].y;
      pf1.u[0] = pk[qt2][2].x; pf1.u[1] = pk[qt2][2].y;
      pf1.u[2] = pk[qt2][3].x; pf1.u[3] = pk[qt2][3].y;
      o[dt][qt2] = __builtin_amdgcn_mfma_f32_16x16x32_bf16(vf0, pf0.v, o[dt][qt2], 0, 0, 0);
      o[dt][qt2] = __builtin_amdgcn_mfma_f32_16x16x32_bf16(vf1, pf1.v, o[dt][qt2], 0, 0, 0);
    }
  }
}

// ---- Flash attention (S^T form, exp2-domain, no-max softmax, register-P) ----
__global__ __launch_bounds__(256, 4) void attn_kernel(
    const bf16* __restrict__ qk, const bf16* __restrict__ vt,
    bf16* __restrict__ aout) {
  int bh = blockIdx.x;   // 0..63 == b*16+h
  int qt = blockIdx.y;   // 0..15
  int bb = bh >> 4, h = bh & 15;
  const bf16* Qg = qk + (size_t)bb * SEQ * 2048 + h * DHEAD;
  const bf16* Kg = Qg + D_MODEL;
  const bf16* Vg = vt + (size_t)bh * DHEAD * SEQ;

  __shared__ __attribute__((aligned(16))) bf16 Qlds[128 * 64];   // 16 KB; KV buf1 after prologue
  __shared__ __attribute__((aligned(16))) bf16 Klds[64 * 64];    //  8 KB; KV buf0 K
  __shared__ __attribute__((aligned(16))) bf16 Vlds[64 * 64];    //  8 KB; KV buf0 V

  int tid = threadIdx.x, wave = tid >> 6, lane = tid & 63;
  int prow = tid >> 3, pch = tid & 7;
  int lch8 = ((pch ^ (prow & 7)) << 3);
  int frow = lane & 15, quad = lane >> 4;
  int e0 = ((quad ^ (frow & 7)) << 3);
  int q0 = qt * 128;

  bf16* K0 = Klds;  bf16* V0 = Vlds;
  bf16* K1 = Qlds;  bf16* V1 = Qlds + 64 * 64;

  const bf16* Kp0 = Kg + (size_t)prow * 2048 + lch8;
  const bf16* Kp1 = Kg + (size_t)(32 + prow) * 2048 + lch8;
  const bf16* Vp0 = Vg + (size_t)prow * SEQ + lch8;
  const bf16* Vp1 = Vg + (size_t)(32 + prow) * SEQ + lch8;
  const size_t KT = (size_t)1 << 17;

#pragma unroll
  for (int s2 = 0; s2 < 4; s2++)
    load_lds16(Qg + (size_t)(q0 + s2 * 32 + prow) * 2048 + lch8,
               (char*)Qlds + s2 * 4096 + tid * 16);
  __syncthreads();
  bf16x8 qf[2][2];
#pragma unroll
  for (int qt2 = 0; qt2 < 2; qt2++)
#pragma unroll
    for (int kk = 0; kk < 2; kk++)
      qf[qt2][kk] =
          *(const bf16x8*)&Qlds[(wave * 32 + qt2 * 16 + frow) * 64 + (e0 ^ (kk * 32))];
  stage_kv(Kp0, Kp1, Vp0, Vp1, K0, V0, tid);
  __syncthreads();

  f32x4 l4[2] = {};
  f32x4 o[4][2] = {};

#pragma unroll 1
  for (int kt = 0; kt < 30; kt += 2) {
    stage_kv(Kp0 + KT, Kp1 + KT, Vp0 + 64, Vp1 + 64, K1, V1, tid);
    kv_tile(K0, V0, frow, e0, qf, l4, o);
    __syncthreads();
    stage_kv(Kp0 + 2 * KT, Kp1 + 2 * KT, Vp0 + 128, Vp1 + 128, K0, V0, tid);
    kv_tile(K1, V1, frow, e0, qf, l4, o);
    __syncthreads();
    Kp0 += 2 * KT; Kp1 += 2 * KT; Vp0 += 128; Vp1 += 128;
  }
  stage_kv(Kp0 + KT, Kp1 + KT, Vp0 + 64, Vp1 + 64, K1, V1, tid);
  kv_tile(K0, V0, frow, e0, qf, l4, o);
  __syncthreads();
  kv_tile(K1, V1, frow, e0, qf, l4, o);

  float linv[2];
#pragma unroll
  for (int qt2 = 0; qt2 < 2; qt2++) {
    float v = (l4[qt2][0] + l4[qt2][1]) + (l4[qt2][2] + l4[qt2][3]);
    v += __shfl_xor(v, 16, 64);
    v += __shfl_xor(v, 32, 64);
    linv[qt2] = 1.f / v;
  }

  __syncthreads();
  bf16* Tw = (wave == 0) ? Qlds
           : (wave == 1) ? Qlds + 32 * 80
           : (wave == 2) ? Klds : Vlds;
#pragma unroll
  for (int qt2 = 0; qt2 < 2; qt2++)
#pragma unroll
    for (int dt = 0; dt < 4; dt++) {
      ushort4 pk;
      pk.x = f2bf(o[dt][qt2][0] * linv[qt2]);
      pk.y = f2bf(o[dt][qt2][1] * linv[qt2]);
      pk.z = f2bf(o[dt][qt2][2] * linv[qt2]);
      pk.w = f2bf(o[dt][qt2][3] * linv[qt2]);
      *(ushort4*)&Tw[(qt2 * 16 + frow) * 80 + dt * 16 + quad * 4] = pk;
    }
  int rq = lane >> 1, d0 = (lane & 1) * 32;
  size_t grow = (size_t)(bb * SEQ + q0 + wave * 32 + rq);
#pragma unroll
  for (int i = 0; i < 4; i++) {
    bf16x8 v8 = *(const bf16x8*)&Tw[rq * 80 + d0 + i * 8];
    *(bf16x8*)&aout[grow * D_MODEL + h * DHEAD + d0 + i * 8] = v8;
  }
}

extern "C" void kernel_launch(void* const* d_in, const int* in_sizes, int n_in,
                              void* d_out, int out_size, void* d_ws, size_t ws_size,
                              hipStream_t stream) {
  const float* x     = (const float*)d_in[0];
  const float* w_qkv = (const float*)d_in[1];
  const float* b_qkv = (const float*)d_in[2];
  const float* w_fc  = (const float*)d_in[3];
  const float* b_fc  = (const float*)d_in[4];
  const float* ln_g  = (const float*)d_in[5];
  const float* ln_b  = (const float*)d_in[6];
  float* out = (float*)d_out;

  char* ws = (char*)d_ws;
  bf16* xn    = (bf16*)(ws);                 // 16 MB (aliased by aout after gemm1)
  bf16* wqkvT = (bf16*)(ws + (16u << 20));   //  6 MB
  bf16* wfcT  = (bf16*)(ws + (22u << 20));   //  2 MB
  bf16* qk    = (bf16*)(ws + (24u << 20));   // 32 MB
  bf16* vt    = (bf16*)(ws + (56u << 20));   // 16 MB -> 72 MB total
  bf16* aout  = (bf16*)(ws);                 // reuses xn region

  ln_kernel<<<NROWS / 4, 256, 0, stream>>>(x, ln_g, ln_b, xn);
  transpose_kernel<<<dim3(128, 32), 256, 0, stream>>>(w_qkv, wqkvT, w_fc, wfcT);
  gemm256_qkv<<<512, 512, 0, stream>>>(xn, wqkvT, b_qkv, qk, vt);
  attn_kernel<<<dim3(NB * NHEAD, SEQ / 128), 256, 0, stream>>>(qk, vt, aout);
  gemm_bt<0, 1, float><<<(NROWS / 128) * (D_MODEL / 128), 256, 0, stream>>>(
      aout, wfcT, b_fc, x, out, nullptr, NROWS, D_MODEL, D_MODEL);
}

// Round 6
// 270.080 us; speedup vs baseline: 1.0315x; 1.0022x over previous
//
#include <hip/hip_runtime.h>
#include <hip/hip_bf16.h>
#include <cstdint>
#include <cstddef>

using bf16 = __hip_bfloat16;
typedef __attribute__((ext_vector_type(4))) float f32x4;
typedef __attribute__((ext_vector_type(8))) short bf16x8;

#define D_MODEL 1024
#define SEQ     2048
#define NB      4
#define NHEAD   16
#define DHEAD   64
#define NROWS   (NB * SEQ)   // 8192

__device__ __forceinline__ void load_lds16(const void* g, void* l) {
  __builtin_amdgcn_global_load_lds(
      (const __attribute__((address_space(1))) unsigned int*)g,
      (__attribute__((address_space(3))) unsigned int*)l, 16, 0, 0);
}

__device__ __forceinline__ unsigned short f2bf(float f) {
  bf16 h = __float2bfloat16(f);
  return *(unsigned short*)&h;
}

// Truncating pack: two f32 -> packed bf16 pair (low = a, high = b). ~1 v_perm.
__device__ __forceinline__ unsigned pk_trunc(float a, float b) {
  union { float f; unsigned u; } ca, cb;
  ca.f = a; cb.f = b;
  return (ca.u >> 16) | (cb.u & 0xffff0000u);
}

// ---------------- LayerNorm: fp32 in, bf16 out; one wave per row ----------------
__global__ __launch_bounds__(256) void ln_kernel(
    const float* __restrict__ x, const float* __restrict__ g,
    const float* __restrict__ bb, bf16* __restrict__ xn) {
  int row  = blockIdx.x * 4 + (threadIdx.x >> 6);
  int lane = threadIdx.x & 63;
  const float4* xr = (const float4*)(x + (size_t)row * D_MODEL);
  float v[16], s = 0.f;
#pragma unroll
  for (int i = 0; i < 4; i++) {
    float4 t = xr[lane + 64 * i];
    v[4 * i] = t.x; v[4 * i + 1] = t.y; v[4 * i + 2] = t.z; v[4 * i + 3] = t.w;
    s += t.x + t.y + t.z + t.w;
  }
#pragma unroll
  for (int off = 32; off; off >>= 1) s += __shfl_xor(s, off, 64);
  float mean = s * (1.f / D_MODEL);
  float vs = 0.f;
#pragma unroll
  for (int i = 0; i < 16; i++) { float d = v[i] - mean; vs += d * d; }
#pragma unroll
  for (int off = 32; off; off >>= 1) vs += __shfl_xor(vs, off, 64);
  float rstd = rsqrtf(vs * (1.f / D_MODEL) + 1e-5f);
  ushort4* op = (ushort4*)(xn + (size_t)row * D_MODEL);
#pragma unroll
  for (int i = 0; i < 4; i++) {
    float4 gv = ((const float4*)g)[lane + 64 * i];
    float4 bv = ((const float4*)bb)[lane + 64 * i];
    ushort4 o;
    o.x = f2bf((v[4 * i]     - mean) * rstd * gv.x + bv.x);
    o.y = f2bf((v[4 * i + 1] - mean) * rstd * gv.y + bv.y);
    o.z = f2bf((v[4 * i + 2] - mean) * rstd * gv.z + bv.z);
    o.w = f2bf((v[4 * i + 3] - mean) * rstd * gv.w + bv.w);
    op[lane + 64 * i] = o;
  }
}

// ------- Fused transpose of both weights: fp32 in[1024][C] -> bf16 out[C][1024] -------
__global__ __launch_bounds__(256) void transpose_kernel(
    const float* __restrict__ w_qkv, bf16* __restrict__ wqkvT,
    const float* __restrict__ w_fc, bf16* __restrict__ wfcT) {
  __shared__ float tile[32][33];
  const float* in; bf16* out; int C, c0;
  if (blockIdx.x < 96) { in = w_qkv; out = wqkvT; C = 3072; c0 = blockIdx.x * 32; }
  else                 { in = w_fc;  out = wfcT;  C = 1024; c0 = (blockIdx.x - 96) * 32; }
  int r0 = blockIdx.y * 32;
  int tx = threadIdx.x & 31, ty = threadIdx.x >> 5;
  for (int i = ty; i < 32; i += 8)
    tile[i][tx] = in[(size_t)(r0 + i) * C + c0 + tx];
  __syncthreads();
  for (int i = ty; i < 32; i += 8)
    out[(size_t)(c0 + i) * 1024 + r0 + tx] = __float2bfloat16(tile[tx][i]);
}

// ======== 8-phase GEMM K-tile with COUNTED vmcnt (T2+T3+T4+T5) ========
// BM=256, BK=64, 512 threads (2M x 4N waves), BCH = B 64-row chunks (BN = 64*BCH... 
// BN = BCH*... per-wave N = BCH*16, BN = 4*BCH*16 = 64*BCH... see callers).
// Stage groups per tile t+1: G1 = {B0..B(BCH-1), A0, A2} consumed at phases 0-1,
// G2 = {A1, A3} consumed at phases 2-3. G1 issued at phase 0 of t, G2 at phase 2.
// Counted waits (never 0 in main loop):
//   P1-end: vmcnt(BCH+2)  -> retires G2(t)   [outstanding G2(t)=2 + G1(t+1)=BCH+2]
//   P3-end: vmcnt(2)      -> retires G1(t+1) [G2(t+1)=2 stays in flight]
// Last tile: P1-end vmcnt(0), no issues, no P3 wait.
template <int BCH, bool STG, bool LAST>
__device__ __forceinline__ void ktile8(
    const bf16* Aw, const bf16* Bw,            // cur LDS buffers (wave-offset)
    bf16* Ad, bf16* Bd,                        // stage destinations (other buf)
    const bf16* const (&Ab)[4], const bf16* const (&Bb)[BCH], size_t koff,
    int tid, int frow, int e_lo, int e_hi, f32x4 (&acc)[8][BCH]) {
  __builtin_amdgcn_sched_barrier(0);
  // ---- phase 0: all B frags + A m0,m1; issue G1(t+1)
  bf16x8 bv[BCH][2];
#pragma unroll
  for (int j = 0; j < BCH; j++) {
    bv[j][0] = *(const bf16x8*)&Bw[(j * 16 + frow) * 64 + e_lo];
    bv[j][1] = *(const bf16x8*)&Bw[(j * 16 + frow) * 64 + e_hi];
  }
  bf16x8 a00 = *(const bf16x8*)&Aw[(frow) * 64 + e_lo];
  bf16x8 a01 = *(const bf16x8*)&Aw[(frow) * 64 + e_hi];
  bf16x8 a10 = *(const bf16x8*)&Aw[(16 + frow) * 64 + e_lo];
  bf16x8 a11 = *(const bf16x8*)&Aw[(16 + frow) * 64 + e_hi];
  if (STG) {
#pragma unroll
    for (int u = 0; u < BCH; u++)
      load_lds16(Bb[u] + koff, (char*)Bd + u * 8192 + tid * 16);
    load_lds16(Ab[0] + koff, (char*)Ad + tid * 16);
    load_lds16(Ab[2] + koff, (char*)Ad + 2 * 8192 + tid * 16);
    __builtin_amdgcn_sched_barrier(0);
  }
  __builtin_amdgcn_s_barrier();
  asm volatile("s_waitcnt lgkmcnt(0)" ::: "memory");
  __builtin_amdgcn_sched_barrier(0);     // rule #18: keep MFMA below the wait
  __builtin_amdgcn_s_setprio(1);
#pragma unroll
  for (int j = 0; j < BCH; j++) {
    acc[0][j] = __builtin_amdgcn_mfma_f32_16x16x32_bf16(a00, bv[j][0], acc[0][j], 0, 0, 0);
    acc[0][j] = __builtin_amdgcn_mfma_f32_16x16x32_bf16(a01, bv[j][1], acc[0][j], 0, 0, 0);
    acc[1][j] = __builtin_amdgcn_mfma_f32_16x16x32_bf16(a10, bv[j][0], acc[1][j], 0, 0, 0);
    acc[1][j] = __builtin_amdgcn_mfma_f32_16x16x32_bf16(a11, bv[j][1], acc[1][j], 0, 0, 0);
  }
  __builtin_amdgcn_s_setprio(0);
  __builtin_amdgcn_s_barrier();
  // ---- phases 1..3
#pragma unroll
  for (int p = 1; p < 4; p++) {
    bf16x8 c00 = *(const bf16x8*)&Aw[((2 * p) * 16 + frow) * 64 + e_lo];
    bf16x8 c01 = *(const bf16x8*)&Aw[((2 * p) * 16 + frow) * 64 + e_hi];
    bf16x8 c10 = *(const bf16x8*)&Aw[((2 * p + 1) * 16 + frow) * 64 + e_lo];
    bf16x8 c11 = *(const bf16x8*)&Aw[((2 * p + 1) * 16 + frow) * 64 + e_hi];
    if (STG && p == 2) {                 // issue G2(t+1) = {A1, A3}
      load_lds16(Ab[1] + koff, (char*)Ad + 1 * 8192 + tid * 16);
      load_lds16(Ab[3] + koff, (char*)Ad + 3 * 8192 + tid * 16);
      __builtin_amdgcn_sched_barrier(0);
    }
    __builtin_amdgcn_s_barrier();
    asm volatile("s_waitcnt lgkmcnt(0)" ::: "memory");
    __builtin_amdgcn_sched_barrier(0);
    __builtin_amdgcn_s_setprio(1);
#pragma unroll
    for (int j = 0; j < BCH; j++) {
      acc[2 * p][j]     = __builtin_amdgcn_mfma_f32_16x16x32_bf16(c00, bv[j][0], acc[2 * p][j], 0, 0, 0);
      acc[2 * p][j]     = __builtin_amdgcn_mfma_f32_16x16x32_bf16(c01, bv[j][1], acc[2 * p][j], 0, 0, 0);
      acc[2 * p + 1][j] = __builtin_amdgcn_mfma_f32_16x16x32_bf16(c10, bv[j][0], acc[2 * p + 1][j], 0, 0, 0);
      acc[2 * p + 1][j] = __builtin_amdgcn_mfma_f32_16x16x32_bf16(c11, bv[j][1], acc[2 * p + 1][j], 0, 0, 0);
    }
    __builtin_amdgcn_s_setprio(0);
    if (p == 1) {                        // retire G2(t) before phases 2-3 read it
      if (LAST) asm volatile("s_waitcnt vmcnt(0)" ::: "memory");
      else if (BCH == 3) asm volatile("s_waitcnt vmcnt(5)" ::: "memory");
      else               asm volatile("s_waitcnt vmcnt(4)" ::: "memory");
      __builtin_amdgcn_sched_barrier(0);
    }
    if (p == 3 && !LAST) {               // retire G1(t+1) before next tile phase 0
      asm volatile("s_waitcnt vmcnt(2)" ::: "memory");
      __builtin_amdgcn_sched_barrier(0);
    }
    __builtin_amdgcn_s_barrier();
  }
}

// ---- 256x192 QKV GEMM: C[8192,3072] = xn @ wqkvT^T + b_qkv, SPLIT epilogue ----
__global__ __launch_bounds__(512, 2) void gemm8_qkv(
    const bf16* __restrict__ A, const bf16* __restrict__ Bt,
    const float* __restrict__ bias, bf16* __restrict__ C, bf16* __restrict__ vt) {
  __shared__ __attribute__((aligned(16))) bf16 AL0[256 * 64];
  __shared__ __attribute__((aligned(16))) bf16 AL1[256 * 64];
  __shared__ __attribute__((aligned(16))) bf16 BL0[192 * 64];
  __shared__ __attribute__((aligned(16))) bf16 BL1[192 * 64];

  // T1: XCD-aware bijective swizzle (512 % 8 == 0)
  int bid = blockIdx.x;
  int logical = (bid & 7) * 64 + (bid >> 3);
  int bm = logical >> 4, bn = logical & 15;
  int m0 = bm * 256, n0 = bn * 192;

  int tid = threadIdx.x, wave = tid >> 6, lane = tid & 63;
  int wm = (wave >> 2) * 128, wn = (wave & 3) * 48;
  int srow = tid >> 3;
  int sw8 = (((tid & 7) ^ (srow & 7)) << 3);
  int frow = lane & 15, quad = lane >> 4;
  int e_lo = ((quad ^ (frow & 7)) << 3);
  int e_hi = (((4 + quad) ^ (frow & 7)) << 3);

  const bf16* Ab[4];
  const bf16* Bb[3];
#pragma unroll
  for (int u = 0; u < 4; u++) Ab[u] = A + (size_t)(m0 + u * 64 + srow) * 1024 + sw8;
#pragma unroll
  for (int u = 0; u < 3; u++) Bb[u] = Bt + (size_t)(n0 + u * 64 + srow) * 1024 + sw8;

  // Prologue: stage K-tile 0 fully, drain once, barrier.
#pragma unroll
  for (int u = 0; u < 3; u++) load_lds16(Bb[u], (char*)BL0 + u * 8192 + tid * 16);
#pragma unroll
  for (int u = 0; u < 4; u++) load_lds16(Ab[u], (char*)AL0 + u * 8192 + tid * 16);
  asm volatile("s_waitcnt vmcnt(0)" ::: "memory");
  __builtin_amdgcn_sched_barrier(0);
  __builtin_amdgcn_s_barrier();

  f32x4 acc[8][3] = {};
  const bf16* A0w = AL0 + wm * 64;
  const bf16* B0w = BL0 + wn * 64;
  const bf16* A1w = AL1 + wm * 64;
  const bf16* B1w = BL1 + wn * 64;

  // 16 K-tiles: loop tiles 0..13 (7x2), peel 14 (stages 15) and 15 (last).
  size_t ko = 64;
#pragma unroll 1
  for (int t2 = 0; t2 < 7; t2++) {
    ktile8<3, true, false>(A0w, B0w, AL1, BL1, Ab, Bb, ko,      tid, frow, e_lo, e_hi, acc);
    ktile8<3, true, false>(A1w, B1w, AL0, BL0, Ab, Bb, ko + 64, tid, frow, e_lo, e_hi, acc);
    ko += 128;
  }
  ktile8<3, true,  false>(A0w, B0w, AL1, BL1, Ab, Bb, ko, tid, frow, e_lo, e_hi, acc);  // t=14
  ktile8<3, false, true >(A1w, B1w, AL0, BL0, Ab, Bb, 0,  tid, frow, e_lo, e_hi, acc);  // t=15

  // ---- SPLIT epilogue (identical math to the verified round-5 version) ----
#pragma unroll
  for (int i = 0; i < 8; i++) {
    int row0 = m0 + wm + i * 16 + (quad << 2);
#pragma unroll
    for (int j = 0; j < 3; j++) {
      int col = n0 + wn + j * 16 + frow;
      float bvs = bias[col];
      if (col >= 2048) {            // V third -> permuted transposed vt
        int hd = col - 2048;
        int b = row0 >> 11, seq0 = row0 & 2047;
        int within = seq0 & 63, mt = within >> 4, q4 = (within >> 2) & 3;
        int pos = (seq0 & ~63) + ((mt >> 1) << 5) + (q4 << 3) + ((mt & 1) << 2);
        ushort4 pk;
        pk.x = f2bf(acc[i][j][0] + bvs);
        pk.y = f2bf(acc[i][j][1] + bvs);
        pk.z = f2bf(acc[i][j][2] + bvs);
        pk.w = f2bf(acc[i][j][3] + bvs);
        *(ushort4*)&vt[((size_t)(b * 1024 + hd)) * SEQ + pos] = pk;
      } else {
        float scale = (col < 1024) ? 0.18033688f : 1.0f;
#pragma unroll
        for (int r = 0; r < 4; r++) {
          size_t idx = (size_t)(row0 + r) * 2048 + col;
          C[idx] = __float2bfloat16((acc[i][j][r] + bvs) * scale);
        }
      }
    }
  }
}

// ---- 256x128 FC GEMM: out[8192,1024] = aout @ wfcT^T + b_fc + x (resid) ----
__global__ __launch_bounds__(512, 2) void gemm8_fc(
    const bf16* __restrict__ A, const bf16* __restrict__ Bt,
    const float* __restrict__ bias, const float* __restrict__ resid,
    float* __restrict__ out) {
  __shared__ __attribute__((aligned(16))) bf16 AL0[256 * 64];
  __shared__ __attribute__((aligned(16))) bf16 AL1[256 * 64];
  __shared__ __attribute__((aligned(16))) bf16 BL0[128 * 64];
  __shared__ __attribute__((aligned(16))) bf16 BL1[128 * 64];

  int bid = blockIdx.x;                       // 256 blocks, 256 % 8 == 0
  int logical = (bid & 7) * 32 + (bid >> 3);
  int bm = logical >> 3, bn = logical & 7;
  int m0 = bm * 256, n0 = bn * 128;

  int tid = threadIdx.x, wave = tid >> 6, lane = tid & 63;
  int wm = (wave >> 2) * 128, wn = (wave & 3) * 32;
  int srow = tid >> 3;
  int sw8 = (((tid & 7) ^ (srow & 7)) << 3);
  int frow = lane & 15, quad = lane >> 4;
  int e_lo = ((quad ^ (frow & 7)) << 3);
  int e_hi = (((4 + quad) ^ (frow & 7)) << 3);

  const bf16* Ab[4];
  const bf16* Bb[2];
#pragma unroll
  for (int u = 0; u < 4; u++) Ab[u] = A + (size_t)(m0 + u * 64 + srow) * 1024 + sw8;
#pragma unroll
  for (int u = 0; u < 2; u++) Bb[u] = Bt + (size_t)(n0 + u * 64 + srow) * 1024 + sw8;

#pragma unroll
  for (int u = 0; u < 2; u++) load_lds16(Bb[u], (char*)BL0 + u * 8192 + tid * 16);
#pragma unroll
  for (int u = 0; u < 4; u++) load_lds16(Ab[u], (char*)AL0 + u * 8192 + tid * 16);
  asm volatile("s_waitcnt vmcnt(0)" ::: "memory");
  __builtin_amdgcn_sched_barrier(0);
  __builtin_amdgcn_s_barrier();

  f32x4 acc[8][2] = {};
  const bf16* A0w = AL0 + wm * 64;
  const bf16* B0w = BL0 + wn * 64;
  const bf16* A1w = AL1 + wm * 64;
  const bf16* B1w = BL1 + wn * 64;

  size_t ko = 64;
#pragma unroll 1
  for (int t2 = 0; t2 < 7; t2++) {
    ktile8<2, true, false>(A0w, B0w, AL1, BL1, Ab, Bb, ko,      tid, frow, e_lo, e_hi, acc);
    ktile8<2, true, false>(A1w, B1w, AL0, BL0, Ab, Bb, ko + 64, tid, frow, e_lo, e_hi, acc);
    ko += 128;
  }
  ktile8<2, true,  false>(A0w, B0w, AL1, BL1, Ab, Bb, ko, tid, frow, e_lo, e_hi, acc);  // t=14
  ktile8<2, false, true >(A1w, B1w, AL0, BL0, Ab, Bb, 0,  tid, frow, e_lo, e_hi, acc);  // t=15

  // ---- RESID epilogue (bit-identical to gemm_bt<0,1,float>) ----
#pragma unroll
  for (int i = 0; i < 8; i++) {
    int row0 = m0 + wm + i * 16 + (quad << 2);
#pragma unroll
    for (int j = 0; j < 2; j++) {
      int col = n0 + wn + j * 16 + frow;
      float bvs = bias[col];
#pragma unroll
      for (int r = 0; r < 4; r++) {
        size_t idx = (size_t)(row0 + r) * 1024 + col;
        out[idx] = (acc[i][j][r] + bvs) + resid[idx];
      }
    }
  }
}

// ---- Flash attention helpers (round-3 best: simple dbuf, one barrier/tile) ----

__device__ __forceinline__ void stage_kv(
    const bf16* Kp0, const bf16* Kp1, const bf16* Vp0, const bf16* Vp1,
    bf16* KB, bf16* VB, int tid) {
  load_lds16(Kp0, (char*)KB + tid * 16);
  load_lds16(Kp1, (char*)KB + 4096 + tid * 16);
  load_lds16(Vp0, (char*)VB + tid * 16);
  load_lds16(Vp1, (char*)VB + 4096 + tid * 16);
}

// One KV tile: S^T = K @ Q^T; p = 2^s packed to bf16 in-register; O^T += V^T @ P^T.
__device__ __forceinline__ void kv_tile(
    const bf16* KL, const bf16* VL, int frow, int e0,
    const bf16x8 (&qf)[2][2], f32x4 (&l4)[2], f32x4 (&o)[4][2]) {
  f32x4 s[4][2] = {};
#pragma unroll
  for (int mt = 0; mt < 4; mt++) {
    bf16x8 af0 = *(const bf16x8*)&KL[(mt * 16 + frow) * 64 + e0];
    bf16x8 af1 = *(const bf16x8*)&KL[(mt * 16 + frow) * 64 + (e0 ^ 32)];
#pragma unroll
    for (int qt2 = 0; qt2 < 2; qt2++) {
      s[mt][qt2] = __builtin_amdgcn_mfma_f32_16x16x32_bf16(af0, qf[qt2][0], s[mt][qt2], 0, 0, 0);
      s[mt][qt2] = __builtin_amdgcn_mfma_f32_16x16x32_bf16(af1, qf[qt2][1], s[mt][qt2], 0, 0, 0);
    }
  }
  uint2 pk[2][4];
#pragma unroll
  for (int qt2 = 0; qt2 < 2; qt2++)
#pragma unroll
    for (int mt = 0; mt < 4; mt++) {
      f32x4 pv;
      pv[0] = __builtin_amdgcn_exp2f(s[mt][qt2][0]);
      pv[1] = __builtin_amdgcn_exp2f(s[mt][qt2][1]);
      pv[2] = __builtin_amdgcn_exp2f(s[mt][qt2][2]);
      pv[3] = __builtin_amdgcn_exp2f(s[mt][qt2][3]);
      l4[qt2] += pv;
      pk[qt2][mt].x = pk_trunc(pv[0], pv[1]);
      pk[qt2][mt].y = pk_trunc(pv[2], pv[3]);
    }
#pragma unroll
  for (int dt = 0; dt < 4; dt++) {
    bf16x8 vf0 = *(const bf16x8*)&VL[(dt * 16 + frow) * 64 + e0];
    bf16x8 vf1 = *(const bf16x8*)&VL[(dt * 16 + frow) * 64 + (e0 ^ 32)];
#pragma unroll
    for (int qt2 = 0; qt2 < 2; qt2++) {
      union { unsigned u[4]; bf16x8 v; } pf0, pf1;
      pf0.u[0] = pk[qt2][0].x; pf0.u[1] = pk[qt2][0].y;
      pf0.u[2] = pk[qt2][1].x; pf0.u[3] = pk[qt2][1].y;
      pf1.u[0] = pk[qt2][2].x; pf1.u[1] = pk[qt2][2].y;
      pf1.u[2] = pk[qt2][3].x; pf1.u[3] = pk[qt2][3].y;
      o[dt][qt2] = __builtin_amdgcn_mfma_f32_16x16x32_bf16(vf0, pf0.v, o[dt][qt2], 0, 0, 0);
      o[dt][qt2] = __builtin_amdgcn_mfma_f32_16x16x32_bf16(vf1, pf1.v, o[dt][qt2], 0, 0, 0);
    }
  }
}

// ---- Flash attention (S^T form, exp2-domain, no-max softmax, register-P) ----
__global__ __launch_bounds__(256, 4) void attn_kernel(
    const bf16* __restrict__ qk, const bf16* __restrict__ vt,
    bf16* __restrict__ aout) {
  int bh = blockIdx.x;   // 0..63 == b*16+h
  int qt = blockIdx.y;   // 0..15
  int bb = bh >> 4, h = bh & 15;
  const bf16* Qg = qk + (size_t)bb * SEQ * 2048 + h * DHEAD;
  const bf16* Kg = Qg + D_MODEL;
  const bf16* Vg = vt + (size_t)bh * DHEAD * SEQ;

  __shared__ __attribute__((aligned(16))) bf16 Qlds[128 * 64];   // 16 KB; KV buf1 after prologue
  __shared__ __attribute__((aligned(16))) bf16 Klds[64 * 64];    //  8 KB; KV buf0 K
  __shared__ __attribute__((aligned(16))) bf16 Vlds[64 * 64];    //  8 KB; KV buf0 V

  int tid = threadIdx.x, wave = tid >> 6, lane = tid & 63;
  int prow = tid >> 3, pch = tid & 7;
  int lch8 = ((pch ^ (prow & 7)) << 3);
  int frow = lane & 15, quad = lane >> 4;
  int e0 = ((quad ^ (frow & 7)) << 3);
  int q0 = qt * 128;

  bf16* K0 = Klds;  bf16* V0 = Vlds;
  bf16* K1 = Qlds;  bf16* V1 = Qlds + 64 * 64;

  const bf16* Kp0 = Kg + (size_t)prow * 2048 + lch8;
  const bf16* Kp1 = Kg + (size_t)(32 + prow) * 2048 + lch8;
  const bf16* Vp0 = Vg + (size_t)prow * SEQ + lch8;
  const bf16* Vp1 = Vg + (size_t)(32 + prow) * SEQ + lch8;
  const size_t KT = (size_t)1 << 17;

#pragma unroll
  for (int s2 = 0; s2 < 4; s2++)
    load_lds16(Qg + (size_t)(q0 + s2 * 32 + prow) * 2048 + lch8,
               (char*)Qlds + s2 * 4096 + tid * 16);
  __syncthreads();
  bf16x8 qf[2][2];
#pragma unroll
  for (int qt2 = 0; qt2 < 2; qt2++)
#pragma unroll
    for (int kk = 0; kk < 2; kk++)
      qf[qt2][kk] =
          *(const bf16x8*)&Qlds[(wave * 32 + qt2 * 16 + frow) * 64 + (e0 ^ (kk * 32))];
  stage_kv(Kp0, Kp1, Vp0, Vp1, K0, V0, tid);
  __syncthreads();

  f32x4 l4[2] = {};
  f32x4 o[4][2] = {};

#pragma unroll 1
  for (int kt = 0; kt < 30; kt += 2) {
    stage_kv(Kp0 + KT, Kp1 + KT, Vp0 + 64, Vp1 + 64, K1, V1, tid);
    kv_tile(K0, V0, frow, e0, qf, l4, o);
    __syncthreads();
    stage_kv(Kp0 + 2 * KT, Kp1 + 2 * KT, Vp0 + 128, Vp1 + 128, K0, V0, tid);
    kv_tile(K1, V1, frow, e0, qf, l4, o);
    __syncthreads();
    Kp0 += 2 * KT; Kp1 += 2 * KT; Vp0 += 128; Vp1 += 128;
  }
  stage_kv(Kp0 + KT, Kp1 + KT, Vp0 + 64, Vp1 + 64, K1, V1, tid);
  kv_tile(K0, V0, frow, e0, qf, l4, o);
  __syncthreads();
  kv_tile(K1, V1, frow, e0, qf, l4, o);

  float linv[2];
#pragma unroll
  for (int qt2 = 0; qt2 < 2; qt2++) {
    float v = (l4[qt2][0] + l4[qt2][1]) + (l4[qt2][2] + l4[qt2][3]);
    v += __shfl_xor(v, 16, 64);
    v += __shfl_xor(v, 32, 64);
    linv[qt2] = 1.f / v;
  }

  __syncthreads();
  bf16* Tw = (wave == 0) ? Qlds
           : (wave == 1) ? Qlds + 32 * 80
           : (wave == 2) ? Klds : Vlds;
#pragma unroll
  for (int qt2 = 0; qt2 < 2; qt2++)
#pragma unroll
    for (int dt = 0; dt < 4; dt++) {
      ushort4 pk;
      pk.x = f2bf(o[dt][qt2][0] * linv[qt2]);
      pk.y = f2bf(o[dt][qt2][1] * linv[qt2]);
      pk.z = f2bf(o[dt][qt2][2] * linv[qt2]);
      pk.w = f2bf(o[dt][qt2][3] * linv[qt2]);
      *(ushort4*)&Tw[(qt2 * 16 + frow) * 80 + dt * 16 + quad * 4] = pk;
    }
  int rq = lane >> 1, d0 = (lane & 1) * 32;
  size_t grow = (size_t)(bb * SEQ + q0 + wave * 32 + rq);
#pragma unroll
  for (int i = 0; i < 4; i++) {
    bf16x8 v8 = *(const bf16x8*)&Tw[rq * 80 + d0 + i * 8];
    *(bf16x8*)&aout[grow * D_MODEL + h * DHEAD + d0 + i * 8] = v8;
  }
}

extern "C" void kernel_launch(void* const* d_in, const int* in_sizes, int n_in,
                              void* d_out, int out_size, void* d_ws, size_t ws_size,
                              hipStream_t stream) {
  const float* x     = (const float*)d_in[0];
  const float* w_qkv = (const float*)d_in[1];
  const float* b_qkv = (const float*)d_in[2];
  const float* w_fc  = (const float*)d_in[3];
  const float* b_fc  = (const float*)d_in[4];
  const float* ln_g  = (const float*)d_in[5];
  const float* ln_b  = (const float*)d_in[6];
  float* out = (float*)d_out;

  char* ws = (char*)d_ws;
  bf16* xn    = (bf16*)(ws);                 // 16 MB (aliased by aout after gemm1)
  bf16* wqkvT = (bf16*)(ws + (16u << 20));   //  6 MB
  bf16* wfcT  = (bf16*)(ws + (22u << 20));   //  2 MB
  bf16* qk    = (bf16*)(ws + (24u << 20));   // 32 MB
  bf16* vt    = (bf16*)(ws + (56u << 20));   // 16 MB -> 72 MB total
  bf16* aout  = (bf16*)(ws);                 // reuses xn region

  ln_kernel<<<NROWS / 4, 256, 0, stream>>>(x, ln_g, ln_b, xn);
  transpose_kernel<<<dim3(128, 32), 256, 0, stream>>>(w_qkv, wqkvT, w_fc, wfcT);
  gemm8_qkv<<<512, 512, 0, stream>>>(xn, wqkvT, b_qkv, qk, vt);
  attn_kernel<<<dim3(NB * NHEAD, SEQ / 128), 256, 0, stream>>>(qk, vt, aout);
  gemm8_fc<<<256, 512, 0, stream>>>(aout, wfcT, b_fc, x, out);
}